// Round 7
// baseline (133.768 us; speedup 1.0000x reference)
//
#include <hip/hip_runtime.h>

#define NPTS 320
#define NCHUNK 8
#define D0 2.0f
#define DSTEP (4.0f / 319.0f)
#define HALFV (765.0f / 512.0f)  // (3/256)*255*0.5
#define DENSITY_C 0.1f
#define INV255 (1.0f / 255.0f)

// 8-byte vector load with only 4-byte guaranteed alignment (x0 is arbitrary).
typedef float f2a __attribute__((ext_vector_type(2), aligned(4)));

// ---------------------------------------------------------------------------
// Repack: fp32 volume -> u8 (q = round(v*255), v in [0,1)). Streaming, full
// HBM BW (not MSHR-bound). 16.7M voxels; 4/thread.
// ---------------------------------------------------------------------------
__global__ __launch_bounds__(256)
void repack_kernel(const float* __restrict__ vol, unsigned char* __restrict__ vol8) {
  const int i = (blockIdx.x * 256 + threadIdx.x) * 4;
  const float4 v = *(const float4*)(vol + i);
  uchar4 q;
  q.x = (unsigned char)(fmaf(v.x, 255.0f, 0.5f));
  q.y = (unsigned char)(fmaf(v.y, 255.0f, 0.5f));
  q.z = (unsigned char)(fmaf(v.z, 255.0f, 0.5f));
  q.w = (unsigned char)(fmaf(v.w, 255.0f, 0.5f));
  *(uchar4*)(vol8 + i) = q;
}

// ---------------------------------------------------------------------------
// Shared ray setup (computes ix(p) = ix0 + p*dix etc. + slab intervals).
// ---------------------------------------------------------------------------
struct RaySetup {
  float ix0, dix, iy0, diy, iz0, diz;
  int i_in_lo, i_in_hi, i_out_lo, i_out_hi;
};

__device__ inline RaySetup ray_setup(int w, int h, const float* R, const float* T) {
  const float xh = (w * (2.0f / 255.0f) - 1.0f) * 0.5f;
  const float yh = (h * (2.0f / 255.0f) - 1.0f) * 0.5f;
  const float R00 = R[0], R01 = R[1], R02 = R[2];
  const float R10 = R[3], R11 = R[4], R12 = R[5];
  const float R20 = R[6], R21 = R[7], R22 = R[8];
  const float T0 = T[0], T1 = T[1], T2 = T[2];
  const float S = 127.5f / HALFV;
  const float Cx = R00 * xh + R01 * yh + R02;
  const float Cy = R10 * xh + R11 * yh + R12;
  const float Cz = R20 * xh + R21 * yh + R22;
  const float Kx = -(R00 * T0 + R01 * T1 + R02 * T2);
  const float Ky = -(R10 * T0 + R11 * T1 + R12 * T2);
  const float Kz = -(R20 * T0 + R21 * T1 + R22 * T2);
  const float ax = Cx * S, bx = Kx * S + 127.5f;
  const float ay = Cy * S, by = Ky * S + 127.5f;
  const float az = Cz * S, bz = Kz * S + 127.5f;
  RaySetup r;
  r.ix0 = ax * D0 + bx; r.dix = ax * DSTEP;
  r.iy0 = ay * D0 + by; r.diy = ay * DSTEP;
  r.iz0 = az * D0 + bz; r.diz = az * DSTEP;

  float plo_in = -1e9f, phi_in = 1e9f, plo_out = -1e9f, phi_out = 1e9f;
  auto slab = [](float a, float b, float L, float H, float& lo, float& hi) {
    if (fabsf(a) < 1e-5f) {
      if (b < L || b > H) { lo = 1e9f; hi = -1e9f; }
    } else {
      const float p1 = (L - b) / a, p2 = (H - b) / a;
      lo = fmaxf(lo, fminf(p1, p2));
      hi = fminf(hi, fmaxf(p1, p2));
    }
  };
  slab(r.dix, r.ix0, 0.01f, 254.99f, plo_in, phi_in);
  slab(r.diy, r.iy0, 0.01f, 254.99f, plo_in, phi_in);
  slab(r.diz, r.iz0, 0.01f, 254.99f, plo_in, phi_in);
  slab(r.dix, r.ix0, -1.01f, 256.01f, plo_out, phi_out);
  slab(r.diy, r.iy0, -1.01f, 256.01f, plo_out, phi_out);
  slab(r.diz, r.iz0, -1.01f, 256.01f, plo_out, phi_out);
  r.i_in_lo  = (int)ceilf(fminf(fmaxf(plo_in, 0.0f), 320.0f));
  r.i_in_hi  = (int)floorf(fminf(fmaxf(phi_in, -1.0f), 319.0f)) + 1;
  r.i_out_lo = (int)ceilf(fminf(fmaxf(plo_out, 0.0f), 320.0f));
  r.i_out_hi = (int)floorf(fminf(fmaxf(phi_out, -1.0f), 319.0f)) + 1;
  return r;
}

// ---------------------------------------------------------------------------
// Kernel: ray-march from the u8 volume. Structure = round-6 (32x2 wave tile,
// block-uniform interval split across 8 waves, lockstep p, fast/masked
// partition). fs is computed in q-units (0..255); the 1/255 scale folds into
// the acc coefficient (lerp is linear). Fetch bytes: 17 MB compulsory vs
// 67 MB fp32 — the R1-R6 invariant dur ~= FETCH/1.4TB/s says this is the
// only lever that moves render time.
// ---------------------------------------------------------------------------
__global__ __launch_bounds__(512, 8)
void render_u8_kernel(const unsigned char* __restrict__ vol8,
                      const float* __restrict__ R,
                      const float* __restrict__ T,
                      float* __restrict__ raw,
                      float* __restrict__ bsum,
                      float* __restrict__ bsumsq,
                      float* __restrict__ bmin,
                      float* __restrict__ bmax) {
  const int lane  = threadIdx.x & 63;
  const int chunk = threadIdx.x >> 6;
  const int w = ((blockIdx.x & 7) << 5) + (lane & 31);
  const int h = ((blockIdx.x >> 3) << 1) + (lane >> 5);

  const RaySetup r = ray_setup(w, h, R, T);
  const float ix0 = r.ix0, dix = r.dix;
  const float iy0 = r.iy0, diy = r.diy;
  const float iz0 = r.iz0, diz = r.diz;

  auto wave_min = [](int v) {
#pragma unroll
    for (int off = 32; off > 0; off >>= 1) v = min(v, __shfl_xor(v, off, 64));
    return v;
  };
  auto wave_max = [](int v) {
#pragma unroll
    for (int off = 32; off > 0; off >>= 1) v = max(v, __shfl_xor(v, off, 64));
    return v;
  };
  const int u_lo   = __builtin_amdgcn_readfirstlane(wave_min(r.i_out_lo));
  const int u_hi   = __builtin_amdgcn_readfirstlane(wave_max(r.i_out_hi));
  const int fin_lo = __builtin_amdgcn_readfirstlane(wave_max(r.i_in_lo));
  const int fin_hi = __builtin_amdgcn_readfirstlane(wave_min(r.i_in_hi));
  const int UL = max(0, u_hi - u_lo);

  const int seg_lo = u_lo + ((chunk * UL) >> 3);
  const int seg_hi = u_lo + (((chunk + 1) * UL) >> 3);
  const int f_lo = min(max(seg_lo, fin_lo), seg_hi);
  const int f_hi = min(max(f_lo, fin_hi), seg_hi);

  float acc = 0.0f;
  float Tac = 1.0f;

  // exact clamped+masked sample (q-units; acc contribution scaled by 1/255)
  auto masked_sample = [&](int p) {
    const float pf = (float)p;
    const float ix = fmaf(pf, dix, ix0);
    const float iy = fmaf(pf, diy, iy0);
    const float iz = fmaf(pf, diz, iz0);
    if (ix > -1.0f && ix < 256.0f && iy > -1.0f && iy < 256.0f &&
        iz > -1.0f && iz < 256.0f) {
      const float xf = floorf(ix), yf = floorf(iy), zf = floorf(iz);
      const float fx = ix - xf, fy = iy - yf, fz = iz - zf;
      const int x0 = (int)xf, y0 = (int)yf, z0 = (int)zf;
      const float wx0 = (x0 >= 0)   ? 1.0f - fx : 0.0f;
      const float wx1 = (x0 <= 254) ? fx        : 0.0f;
      const float wy0 = (y0 >= 0)   ? 1.0f - fy : 0.0f;
      const float wy1 = (y0 <= 254) ? fy        : 0.0f;
      const float wz0 = (z0 >= 0)   ? 1.0f - fz : 0.0f;
      const float wz1 = (z0 <= 254) ? fz        : 0.0f;
      const int xc0 = max(x0, 0),     xc1 = min(x0 + 1, 255);
      const int yc0 = max(y0, 0),     yc1 = min(y0 + 1, 255);
      const int zc0 = max(z0, 0),     zc1 = min(z0 + 1, 255);
      const int b00 = (zc0 * 256 + yc0) * 256;
      const int b01 = (zc0 * 256 + yc1) * 256;
      const int b10 = (zc1 * 256 + yc0) * 256;
      const int b11 = (zc1 * 256 + yc1) * 256;
      const float v000 = (float)vol8[b00 + xc0], v001 = (float)vol8[b00 + xc1];
      const float v010 = (float)vol8[b01 + xc0], v011 = (float)vol8[b01 + xc1];
      const float v100 = (float)vol8[b10 + xc0], v101 = (float)vol8[b10 + xc1];
      const float v110 = (float)vol8[b11 + xc0], v111 = (float)vol8[b11 + xc1];
      const float fs =
          wz0 * (wy0 * (wx0 * v000 + wx1 * v001) +
                 wy1 * (wx0 * v010 + wx1 * v011)) +
          wz1 * (wy0 * (wx0 * v100 + wx1 * v101) +
                 wy1 * (wx0 * v110 + wx1 * v111));
      const float wsum  = (wx0 + wx1) * (wy0 + wy1) * (wz0 + wz1);
      const float sigma = DENSITY_C * wsum;
      acc = fmaf(sigma * Tac * INV255, fs, acc);
      Tac *= (1.0f + 1e-10f - sigma);
    } else {
      Tac *= (1.0f + 1e-10f);
    }
  };

  // interior sample in q-units: 8 ubyte loads (inst count is NOT the
  // bottleneck — fetched bytes are), no clamps/masks
  auto fast_sample = [&](int p) -> float {
    const float pf = (float)p;
    const float ix = fmaf(pf, dix, ix0);
    const float iy = fmaf(pf, diy, iy0);
    const float iz = fmaf(pf, diz, iz0);
    const int x0 = (int)ix, y0 = (int)iy, z0 = (int)iz;
    const float fx = ix - (float)x0;
    const float fy = iy - (float)y0;
    const float fz = iz - (float)z0;
    const int base = (z0 << 16) + (y0 << 8) + x0;
    const float v000 = (float)vol8[base],         v001 = (float)vol8[base + 1];
    const float v010 = (float)vol8[base + 256],   v011 = (float)vol8[base + 257];
    const float v100 = (float)vol8[base + 65536], v101 = (float)vol8[base + 65537];
    const float v110 = (float)vol8[base + 65792], v111 = (float)vol8[base + 65793];
    const float c00 = fmaf(fx, v001 - v000, v000);
    const float c01 = fmaf(fx, v011 - v010, v010);
    const float c10 = fmaf(fx, v101 - v100, v100);
    const float c11 = fmaf(fx, v111 - v110, v110);
    const float c0  = fmaf(fy, c01 - c00, c00);
    const float c1  = fmaf(fy, c11 - c10, c10);
    return fmaf(fz, c1 - c0, c0);
  };

  for (int p = seg_lo; p < f_lo; ++p) masked_sample(p);

  int p = f_lo;
#pragma unroll 2
  for (; p + 4 <= f_hi; p += 4) {
    const float fs0 = fast_sample(p);
    const float fs1 = fast_sample(p + 1);
    const float fs2 = fast_sample(p + 2);
    const float fs3 = fast_sample(p + 3);
    const float g = fmaf(0.729f, fs3,
                    fmaf(0.81f,  fs2,
                    fmaf(0.9f,   fs1, fs0)));
    acc = fmaf(Tac * (DENSITY_C * INV255), g, acc);
    Tac *= 0.6561f;   // 0.9^4
  }
  for (; p < f_hi; ++p) {
    const float fs = fast_sample(p);
    acc = fmaf(Tac * (DENSITY_C * INV255), fs, acc);
    Tac *= (1.0f - DENSITY_C);
  }

  for (p = f_hi; p < seg_hi; ++p) masked_sample(p);

  __shared__ float lrgb[NCHUNK][64];
  __shared__ float lT[NCHUNK][64];
  lrgb[chunk][lane] = acc;
  lT[chunk][lane]   = Tac;
  __syncthreads();

  if (threadIdx.x < 64) {
    float a = 0.0f, Tp = 1.0f;
#pragma unroll
    for (int c = 0; c < NCHUNK; ++c) {
      a  = fmaf(Tp, lrgb[c][lane], a);
      Tp *= lT[c][lane];
    }
    raw[h * 256 + w] = a;

    float s = a, q = a * a, mn = a, mx = a;
#pragma unroll
    for (int off = 32; off > 0; off >>= 1) {
      s += __shfl_down(s, off, 64);
      q += __shfl_down(q, off, 64);
      mn = fminf(mn, __shfl_down(mn, off, 64));
      mx = fmaxf(mx, __shfl_down(mx, off, 64));
    }
    if (lane == 0) {
      bsum[blockIdx.x]   = s;
      bsumsq[blockIdx.x] = q;
      bmin[blockIdx.x]   = mn;
      bmax[blockIdx.x]   = mx;
    }
  }
}

// ---------------------------------------------------------------------------
// Fallback fp32 render (round-6 kernel) — used only if ws_size can't hold
// the u8 volume. Same structure, reads fp32 vol directly.
// ---------------------------------------------------------------------------
__global__ __launch_bounds__(512, 8)
void render_f32_kernel(const float* __restrict__ vol,
                       const float* __restrict__ R,
                       const float* __restrict__ T,
                       float* __restrict__ raw,
                       float* __restrict__ bsum,
                       float* __restrict__ bsumsq,
                       float* __restrict__ bmin,
                       float* __restrict__ bmax) {
  const int lane  = threadIdx.x & 63;
  const int chunk = threadIdx.x >> 6;
  const int w = ((blockIdx.x & 7) << 5) + (lane & 31);
  const int h = ((blockIdx.x >> 3) << 1) + (lane >> 5);

  const RaySetup r = ray_setup(w, h, R, T);
  const float ix0 = r.ix0, dix = r.dix;
  const float iy0 = r.iy0, diy = r.diy;
  const float iz0 = r.iz0, diz = r.diz;

  auto wave_min = [](int v) {
#pragma unroll
    for (int off = 32; off > 0; off >>= 1) v = min(v, __shfl_xor(v, off, 64));
    return v;
  };
  auto wave_max = [](int v) {
#pragma unroll
    for (int off = 32; off > 0; off >>= 1) v = max(v, __shfl_xor(v, off, 64));
    return v;
  };
  const int u_lo   = __builtin_amdgcn_readfirstlane(wave_min(r.i_out_lo));
  const int u_hi   = __builtin_amdgcn_readfirstlane(wave_max(r.i_out_hi));
  const int fin_lo = __builtin_amdgcn_readfirstlane(wave_max(r.i_in_lo));
  const int fin_hi = __builtin_amdgcn_readfirstlane(wave_min(r.i_in_hi));
  const int UL = max(0, u_hi - u_lo);
  const int seg_lo = u_lo + ((chunk * UL) >> 3);
  const int seg_hi = u_lo + (((chunk + 1) * UL) >> 3);
  const int f_lo = min(max(seg_lo, fin_lo), seg_hi);
  const int f_hi = min(max(f_lo, fin_hi), seg_hi);

  float acc = 0.0f, Tac = 1.0f;

  auto masked_sample = [&](int p) {
    const float pf = (float)p;
    const float ix = fmaf(pf, dix, ix0);
    const float iy = fmaf(pf, diy, iy0);
    const float iz = fmaf(pf, diz, iz0);
    if (ix > -1.0f && ix < 256.0f && iy > -1.0f && iy < 256.0f &&
        iz > -1.0f && iz < 256.0f) {
      const float xf = floorf(ix), yf = floorf(iy), zf = floorf(iz);
      const float fx = ix - xf, fy = iy - yf, fz = iz - zf;
      const int x0 = (int)xf, y0 = (int)yf, z0 = (int)zf;
      const float wx0 = (x0 >= 0)   ? 1.0f - fx : 0.0f;
      const float wx1 = (x0 <= 254) ? fx        : 0.0f;
      const float wy0 = (y0 >= 0)   ? 1.0f - fy : 0.0f;
      const float wy1 = (y0 <= 254) ? fy        : 0.0f;
      const float wz0 = (z0 >= 0)   ? 1.0f - fz : 0.0f;
      const float wz1 = (z0 <= 254) ? fz        : 0.0f;
      const int xc0 = max(x0, 0),     xc1 = min(x0 + 1, 255);
      const int yc0 = max(y0, 0),     yc1 = min(y0 + 1, 255);
      const int zc0 = max(z0, 0),     zc1 = min(z0 + 1, 255);
      const int b00 = (zc0 * 256 + yc0) * 256;
      const int b01 = (zc0 * 256 + yc1) * 256;
      const int b10 = (zc1 * 256 + yc0) * 256;
      const int b11 = (zc1 * 256 + yc1) * 256;
      const float v000 = vol[b00 + xc0], v001 = vol[b00 + xc1];
      const float v010 = vol[b01 + xc0], v011 = vol[b01 + xc1];
      const float v100 = vol[b10 + xc0], v101 = vol[b10 + xc1];
      const float v110 = vol[b11 + xc0], v111 = vol[b11 + xc1];
      const float fs =
          wz0 * (wy0 * (wx0 * v000 + wx1 * v001) +
                 wy1 * (wx0 * v010 + wx1 * v011)) +
          wz1 * (wy0 * (wx0 * v100 + wx1 * v101) +
                 wy1 * (wx0 * v110 + wx1 * v111));
      const float wsum  = (wx0 + wx1) * (wy0 + wy1) * (wz0 + wz1);
      const float sigma = DENSITY_C * wsum;
      acc = fmaf(sigma * Tac, fs, acc);
      Tac *= (1.0f + 1e-10f - sigma);
    } else {
      Tac *= (1.0f + 1e-10f);
    }
  };

  auto fast_sample = [&](int p) -> float {
    const float pf = (float)p;
    const float ix = fmaf(pf, dix, ix0);
    const float iy = fmaf(pf, diy, iy0);
    const float iz = fmaf(pf, diz, iz0);
    const int x0 = (int)ix, y0 = (int)iy, z0 = (int)iz;
    const float fx = ix - (float)x0;
    const float fy = iy - (float)y0;
    const float fz = iz - (float)z0;
    const int base = (z0 << 16) + (y0 << 8) + x0;
    const f2a v00 = *(const f2a*)(vol + base);
    const f2a v01 = *(const f2a*)(vol + base + 256);
    const f2a v10 = *(const f2a*)(vol + base + 65536);
    const f2a v11 = *(const f2a*)(vol + base + 65792);
    const float c00 = fmaf(fx, v00.y - v00.x, v00.x);
    const float c01 = fmaf(fx, v01.y - v01.x, v01.x);
    const float c10 = fmaf(fx, v10.y - v10.x, v10.x);
    const float c11 = fmaf(fx, v11.y - v11.x, v11.x);
    const float c0  = fmaf(fy, c01 - c00, c00);
    const float c1  = fmaf(fy, c11 - c10, c10);
    return fmaf(fz, c1 - c0, c0);
  };

  for (int p = seg_lo; p < f_lo; ++p) masked_sample(p);
  int p = f_lo;
#pragma unroll 2
  for (; p + 4 <= f_hi; p += 4) {
    const float fs0 = fast_sample(p);
    const float fs1 = fast_sample(p + 1);
    const float fs2 = fast_sample(p + 2);
    const float fs3 = fast_sample(p + 3);
    const float g = fmaf(0.729f, fs3,
                    fmaf(0.81f,  fs2,
                    fmaf(0.9f,   fs1, fs0)));
    acc = fmaf(Tac * DENSITY_C, g, acc);
    Tac *= 0.6561f;
  }
  for (; p < f_hi; ++p) {
    const float fs = fast_sample(p);
    acc = fmaf(Tac * DENSITY_C, fs, acc);
    Tac *= (1.0f - DENSITY_C);
  }
  for (p = f_hi; p < seg_hi; ++p) masked_sample(p);

  __shared__ float lrgb[NCHUNK][64];
  __shared__ float lT[NCHUNK][64];
  lrgb[chunk][lane] = acc;
  lT[chunk][lane]   = Tac;
  __syncthreads();

  if (threadIdx.x < 64) {
    float a = 0.0f, Tp = 1.0f;
#pragma unroll
    for (int c = 0; c < NCHUNK; ++c) {
      a  = fmaf(Tp, lrgb[c][lane], a);
      Tp *= lT[c][lane];
    }
    raw[h * 256 + w] = a;
    float s = a, q = a * a, mn = a, mx = a;
#pragma unroll
    for (int off = 32; off > 0; off >>= 1) {
      s += __shfl_down(s, off, 64);
      q += __shfl_down(q, off, 64);
      mn = fminf(mn, __shfl_down(mn, off, 64));
      mx = fmaxf(mx, __shfl_down(mx, off, 64));
    }
    if (lane == 0) {
      bsum[blockIdx.x]   = s;
      bsumsq[blockIdx.x] = q;
      bmin[blockIdx.x]   = mn;
      bmax[blockIdx.x]   = mx;
    }
  }
}

// ---------------------------------------------------------------------------
// Fused stats + normalize + transpose (unchanged from round 6).
// ---------------------------------------------------------------------------
__global__ __launch_bounds__(256)
void finalize_kernel(const float* __restrict__ raw,
                     const float* __restrict__ bsum,
                     const float* __restrict__ bsumsq,
                     const float* __restrict__ bmin,
                     const float* __restrict__ bmax,
                     float* __restrict__ out) {
  __shared__ double wS[4], wQ[4];
  __shared__ float wMn[4], wMx[4];
  const int t = threadIdx.x;
  const int lane = t & 63, wv = t >> 6;

  double s = 0.0, q = 0.0;
  float mn = 3.4e38f, mx = -3.4e38f;
#pragma unroll
  for (int i = 0; i < 4; ++i) {
    const int idx = t + i * 256;
    s += (double)bsum[idx];
    q += (double)bsumsq[idx];
    mn = fminf(mn, bmin[idx]);
    mx = fmaxf(mx, bmax[idx]);
  }
#pragma unroll
  for (int off = 32; off > 0; off >>= 1) {
    s += __shfl_down(s, off, 64);
    q += __shfl_down(q, off, 64);
    mn = fminf(mn, __shfl_down(mn, off, 64));
    mx = fmaxf(mx, __shfl_down(mx, off, 64));
  }
  if (lane == 0) { wS[wv] = s; wQ[wv] = q; wMn[wv] = mn; wMx[wv] = mx; }
  __syncthreads();
  const double sum   = wS[0] + wS[1] + wS[2] + wS[3];
  const double sumsq = wQ[0] + wQ[1] + wQ[2] + wQ[3];
  const float  gmn = fminf(fminf(wMn[0], wMn[1]), fminf(wMn[2], wMn[3]));
  const float  gmx = fmaxf(fmaxf(wMx[0], wMx[1]), fmaxf(wMx[2], wMx[3]));

  const double N = 65536.0;
  const double mean = sum / N;
  double var = (sumsq - sum * sum / N) / (N - 1.0);
  if (var < 0.0) var = 0.0;
  const float stdeps = (float)sqrt(var) + 1e-8f;
  const float inv_std = 1.0f / stdeps;
  const float fmean = (float)mean;
  const float smin = (gmn - fmean) * inv_std;
  const float smax = (gmx - fmean) * inv_std;
  const float inv_range = 1.0f / (smax - smin + 1e-8f);

  const int o = blockIdx.x * 256 + t;
  const int wq = o >> 8;
  const int hq = o & 255;
  const float sv = (raw[hq * 256 + wq] - fmean) * inv_std;
  out[o] = (sv - smin + 1e-8f) * inv_range;
}

extern "C" void kernel_launch(void* const* d_in, const int* in_sizes, int n_in,
                              void* d_out, int out_size, void* d_ws, size_t ws_size,
                              hipStream_t stream) {
  const float* vol = (const float*)d_in[0];  // (256,256,256) fp32
  const float* R   = (const float*)d_in[1];  // (1,3,3)
  const float* T   = (const float*)d_in[2];  // (1,3)
  float* out = (float*)d_out;                // 65536 fp32

  float* raw    = (float*)d_ws;              // 65536 f32
  float* bsum   = raw + 65536;               // 1024
  float* bsumsq = bsum + 1024;               // 1024
  float* bmin   = bsumsq + 1024;             // 1024
  float* bmax   = bmin + 1024;               // 1024
  unsigned char* vol8 = (unsigned char*)(bmax + 1024);  // 16,777,216 B
  const size_t need = (size_t)(65536 + 4 * 1024) * 4 + (size_t)16777216;

  if (ws_size >= need) {
    repack_kernel<<<16384, 256, 0, stream>>>(vol, vol8);
    render_u8_kernel<<<1024, 512, 0, stream>>>(vol8, R, T, raw, bsum, bsumsq, bmin, bmax);
  } else {
    render_f32_kernel<<<1024, 512, 0, stream>>>(vol, R, T, raw, bsum, bsumsq, bmin, bmax);
  }
  finalize_kernel<<<256, 256, 0, stream>>>(raw, bsum, bsumsq, bmin, bmax, out);
}